// Round 3
// baseline (255.801 us; speedup 1.0000x reference)
//
#include <hip/hip_runtime.h>
#include <cstdio>

// MHA block for MI355X (gfx950). Round 2:
//  - attn: split-K across waves, K/V direct global->reg (no LDS staging, no
//    main-loop barriers), per-wave P slice in LDS, fp32 cross-wave merge.
//  - gemm: 128x128 tile BK=32 (4x4 frags/wave), cvt_pk staging.
// ws layout (bf16): Q[S][768] | K[S][768] | Vt[768][S] | AO[S][768].

using u16 = unsigned short;
typedef __bf16 bf16x8 __attribute__((ext_vector_type(8)));
typedef float f32x4 __attribute__((ext_vector_type(4)));
typedef unsigned int u32x4 __attribute__((ext_vector_type(4)));
typedef unsigned int u32x2 __attribute__((ext_vector_type(2)));
typedef u16 u16x4 __attribute__((ext_vector_type(4)));

constexpr int SEQ = 4096;
constexpr int DIM = 768;
constexpr int NH = 12;
constexpr int HD = 64;
// (1/sqrt(64)) * log2(e), folded into Q projection
constexpr float SM_PRE = 0.18033688011112042f;
constexpr float DEFER_THR = 8.0f;  // exp2-domain defer-max threshold (T13)

__device__ __forceinline__ u16 f2bf(float f) {
  union { float f; unsigned u; } v{f};
  unsigned r = v.u + 0x7fffu + ((v.u >> 16) & 1u);  // RNE
  return (u16)(r >> 16);
}
__device__ __forceinline__ unsigned cvtpk_bf16(float a, float b) {
  unsigned r;
  asm("v_cvt_pk_bf16_f32 %0, %1, %2" : "=v"(r) : "v"(a), "v"(b));
  return r;  // lo16 = bf16(a), hi16 = bf16(b)
}
__device__ __forceinline__ bf16x8 ldg_frag(const u16* p) {
  return __builtin_bit_cast(bf16x8, *(const u32x4*)p);
}

// ---------------- GEMM: out = scale*(A @ W^T + bias) ----------------
// A: [4096][768] fp32 or bf16. W: [768][768] fp32 (row = out col).
// OUT_MODE: 0 = fp32 row-major, 1 = bf16 row-major (scaled), 2 = bf16 transposed
template <bool IN_BF16, int OUT_MODE>
__global__ __launch_bounds__(256) void gemm_bias(const void* __restrict__ Ap,
                                                 const float* __restrict__ W,
                                                 const float* __restrict__ bias,
                                                 void* __restrict__ outp,
                                                 float scale) {
  constexpr int LDA = 40;  // 32 + 8 pad (80B rows)
  __shared__ alignas(16) u16 As[128 * LDA];
  __shared__ alignas(16) u16 Bs[128 * LDA];

  const int tid = threadIdx.x;
  const int lane = tid & 63, wave = tid >> 6;
  const int lg = lane >> 4, ln = lane & 15;
  const int wr = wave >> 1, wc = wave & 1;
  const int m0 = blockIdx.y * 128;
  const int n0 = blockIdx.x * 128;
  const int srow = tid >> 1;          // 0..127
  const int scol = (tid & 1) * 16;    // 0 or 16 (k elems)

  f32x4 acc[4][4] = {};

  for (int kk = 0; kk < DIM; kk += 32) {
    // ---- stage A tile [128][32] -> bf16 LDS ----
    if constexpr (IN_BF16) {
      const u16* Ab = (const u16*)Ap;
      const u32x4* src = (const u32x4*)(Ab + (size_t)(m0 + srow) * DIM + kk + scol);
      *(u32x4*)&As[srow * LDA + scol] = src[0];
      *(u32x4*)&As[srow * LDA + scol + 8] = src[1];
    } else {
      const float* Af = (const float*)Ap;
      const float* a = Af + (size_t)(m0 + srow) * DIM + kk + scol;
      float4 f0 = *(const float4*)(a);
      float4 f1 = *(const float4*)(a + 4);
      float4 f2 = *(const float4*)(a + 8);
      float4 f3 = *(const float4*)(a + 12);
      u32x4 w0 = {cvtpk_bf16(f0.x, f0.y), cvtpk_bf16(f0.z, f0.w),
                  cvtpk_bf16(f1.x, f1.y), cvtpk_bf16(f1.z, f1.w)};
      u32x4 w1 = {cvtpk_bf16(f2.x, f2.y), cvtpk_bf16(f2.z, f2.w),
                  cvtpk_bf16(f3.x, f3.y), cvtpk_bf16(f3.z, f3.w)};
      *(u32x4*)&As[srow * LDA + scol] = w0;
      *(u32x4*)&As[srow * LDA + scol + 8] = w1;
    }
    // ---- stage B tile from W (fp32 always) ----
    {
      const float* b = W + (size_t)(n0 + srow) * DIM + kk + scol;
      float4 f0 = *(const float4*)(b);
      float4 f1 = *(const float4*)(b + 4);
      float4 f2 = *(const float4*)(b + 8);
      float4 f3 = *(const float4*)(b + 12);
      u32x4 w0 = {cvtpk_bf16(f0.x, f0.y), cvtpk_bf16(f0.z, f0.w),
                  cvtpk_bf16(f1.x, f1.y), cvtpk_bf16(f1.z, f1.w)};
      u32x4 w1 = {cvtpk_bf16(f2.x, f2.y), cvtpk_bf16(f2.z, f2.w),
                  cvtpk_bf16(f3.x, f3.y), cvtpk_bf16(f3.z, f3.w)};
      *(u32x4*)&Bs[srow * LDA + scol] = w0;
      *(u32x4*)&Bs[srow * LDA + scol + 8] = w1;
    }
    __syncthreads();

    bf16x8 af[4], bfr[4];
#pragma unroll
    for (int i = 0; i < 4; ++i)
      af[i] = __builtin_bit_cast(bf16x8, *(const u32x4*)&As[(wr * 64 + i * 16 + ln) * LDA + lg * 8]);
#pragma unroll
    for (int j = 0; j < 4; ++j)
      bfr[j] = __builtin_bit_cast(bf16x8, *(const u32x4*)&Bs[(wc * 64 + j * 16 + ln) * LDA + lg * 8]);
#pragma unroll
    for (int i = 0; i < 4; ++i)
#pragma unroll
      for (int j = 0; j < 4; ++j)
        acc[i][j] = __builtin_amdgcn_mfma_f32_16x16x32_bf16(af[i], bfr[j], acc[i][j], 0, 0, 0);
    __syncthreads();
  }

  // epilogue: C row = wr*64+i*16+lg*4+r, col = wc*64+j*16+ln
#pragma unroll
  for (int i = 0; i < 4; ++i) {
    const int rowb = m0 + wr * 64 + i * 16 + lg * 4;
#pragma unroll
    for (int j = 0; j < 4; ++j) {
      const int col = n0 + wc * 64 + j * 16 + ln;
      const float bv = bias[col];
      if constexpr (OUT_MODE == 0) {
        float* out = (float*)outp;
#pragma unroll
        for (int r = 0; r < 4; ++r) out[(size_t)(rowb + r) * DIM + col] = acc[i][j][r] + bv;
      } else if constexpr (OUT_MODE == 1) {
        u16* out = (u16*)outp;
#pragma unroll
        for (int r = 0; r < 4; ++r)
          out[(size_t)(rowb + r) * DIM + col] = f2bf((acc[i][j][r] + bv) * scale);
      } else {
        u16* out = (u16*)outp;
        u16x4 pk;
#pragma unroll
        for (int r = 0; r < 4; ++r) pk[r] = f2bf(acc[i][j][r] + bv);
        *(u16x4*)&out[(size_t)col * SEQ + rowb] = pk;
      }
    }
  }
}

// ---------------- Flash attention, wave-split-K ----------------
// Grid (SEQ/64, NH), 4 waves. Block = 64 q rows; wave w owns keys t*128+w*32.
// Wave-private (m,l,oacc) for all 64 q; fp32 cross-wave merge at the end.
// Q,K: [S][768] bf16 (Q prescaled by SM_PRE). Vt: [768][S] bf16. AO: [S][768] bf16.
__global__ __launch_bounds__(256, 3) void attn_kernel(const u16* __restrict__ Q,
                                                      const u16* __restrict__ K,
                                                      const u16* __restrict__ Vt,
                                                      u16* __restrict__ AO) {
  constexpr int LDP = 40;  // P slice stride: 32 keys + 8 pad
  constexpr int LDO = 68;  // merge stride: 64 d + 4 pad (f32)
  __shared__ alignas(16) u16 Ps[4][64 * LDP];
  __shared__ alignas(16) float Om[64 * LDO];
  __shared__ float smx[4][64], slx[4][64], sLf[64];

  const int tid = threadIdx.x, lane = tid & 63, wave = tid >> 6;
  const int lg = lane >> 4, ln = lane & 15;
  const int h = blockIdx.y;
  const int q0 = blockIdx.x * 64;

  // Q fragments (B-frag of mfma(K,Q)): q = q0+jq*16+ln, k(d) = c*32+lg*8+j
  bf16x8 qf[4][2];
#pragma unroll
  for (int jq = 0; jq < 4; ++jq) {
    const u16* qp = Q + (size_t)(q0 + jq * 16 + ln) * DIM + h * HD + lg * 8;
    qf[jq][0] = ldg_frag(qp);
    qf[jq][1] = ldg_frag(qp + 32);
  }

  float m_[4], l_[4];
#pragma unroll
  for (int jq = 0; jq < 4; ++jq) { m_[jq] = -1e30f; l_[jq] = 0.f; }
  f32x4 oacc[4][4] = {};  // [jq][nd]: O[q=jq*16+lg*4+r][d=nd*16+ln]

  const u16* Kb = K + (size_t)h * HD;
  const u16* Vb = Vt + (size_t)h * HD * SEQ;

  for (int t = 0; t < SEQ / 128; ++t) {
    const int kbase = t * 128 + wave * 32;

    // K A-frags direct from global: key = kbase+jt*16+ln, k(d) = c*32+lg*8+j
    bf16x8 kf[2][2];
#pragma unroll
    for (int jt = 0; jt < 2; ++jt) {
      const u16* kp = Kb + (size_t)(kbase + jt * 16 + ln) * DIM + lg * 8;
      kf[jt][0] = ldg_frag(kp);
      kf[jt][1] = ldg_frag(kp + 32);
    }

    // S^T = K Q^T : st[jq][jt], col=ln->q, row=lg*4+r -> key=kbase+jt*16+lg*4+r
    f32x4 st[4][2];
#pragma unroll
    for (int jq = 0; jq < 4; ++jq)
#pragma unroll
      for (int jt = 0; jt < 2; ++jt) {
        f32x4 s = __builtin_amdgcn_mfma_f32_16x16x32_bf16(kf[jt][0], qf[jq][0],
                                                          f32x4{}, 0, 0, 0);
        st[jq][jt] =
            __builtin_amdgcn_mfma_f32_16x16x32_bf16(kf[jt][1], qf[jq][1], s, 0, 0, 0);
      }

    // per-jq tile max (8 in-lane + 2 cross-lg shfl)
    float pmax[4];
    bool need = false;
#pragma unroll
    for (int jq = 0; jq < 4; ++jq) {
      f32x4 s0 = st[jq][0], s1 = st[jq][1];
      float p = fmaxf(fmaxf(fmaxf(s0[0], s0[1]), fmaxf(s0[2], s0[3])),
                      fmaxf(fmaxf(s1[0], s1[1]), fmaxf(s1[2], s1[3])));
      p = fmaxf(p, __shfl_xor(p, 16));
      p = fmaxf(p, __shfl_xor(p, 32));
      pmax[jq] = p;
      need = need || (p > m_[jq] + DEFER_THR);
    }

    if (__ballot(need)) {  // rare after warm-up (T13)
#pragma unroll
      for (int jq = 0; jq < 4; ++jq) {
        const float mn = fmaxf(m_[jq], pmax[jq]);
        const float scl = __builtin_amdgcn_exp2f(m_[jq] - mn);
        m_[jq] = mn;
        l_[jq] *= scl;
        float sr[4];
#pragma unroll
        for (int r = 0; r < 4; ++r) sr[r] = __shfl(scl, lg * 4 + r);
#pragma unroll
        for (int nd = 0; nd < 4; ++nd)
#pragma unroll
          for (int r = 0; r < 4; ++r) oacc[jq][nd][r] *= sr[r];
      }
    }

    // V B-frags direct from global: d = nd*16+ln, k(key) = kbase+lg*8+j
    bf16x8 vf[4];
#pragma unroll
    for (int nd = 0; nd < 4; ++nd)
      vf[nd] = ldg_frag(Vb + (size_t)(nd * 16 + ln) * SEQ + kbase + lg * 8);

    // P = exp2(st - m), row-sum, pack -> per-wave LDS slice
#pragma unroll
    for (int jq = 0; jq < 4; ++jq) {
      f32x4 e0, e1;
#pragma unroll
      for (int r = 0; r < 4; ++r) {
        e0[r] = __builtin_amdgcn_exp2f(st[jq][0][r] - m_[jq]);
        e1[r] = __builtin_amdgcn_exp2f(st[jq][1][r] - m_[jq]);
      }
      float rs = ((e0[0] + e0[1]) + (e0[2] + e0[3])) +
                 ((e1[0] + e1[1]) + (e1[2] + e1[3]));
      rs += __shfl_xor(rs, 16);
      rs += __shfl_xor(rs, 32);
      l_[jq] += rs;
      u32x2 w0, w1;
      w0[0] = cvtpk_bf16(e0[0], e0[1]);
      w0[1] = cvtpk_bf16(e0[2], e0[3]);
      w1[0] = cvtpk_bf16(e1[0], e1[1]);
      w1[1] = cvtpk_bf16(e1[2], e1[3]);
      *(u32x2*)&Ps[wave][(jq * 16 + ln) * LDP + lg * 4] = w0;
      *(u32x2*)&Ps[wave][(jq * 16 + ln) * LDP + 16 + lg * 4] = w1;
    }

    // P A-frags: q = jq*16+ln, k(key) = lg*8+j  (same-wave LDS, no barrier)
    bf16x8 pf[4];
#pragma unroll
    for (int jq = 0; jq < 4; ++jq)
      pf[jq] = __builtin_bit_cast(bf16x8,
                                  *(const u32x4*)&Ps[wave][(jq * 16 + ln) * LDP + lg * 8]);

    // O += P V
#pragma unroll
    for (int jq = 0; jq < 4; ++jq)
#pragma unroll
      for (int nd = 0; nd < 4; ++nd)
        oacc[jq][nd] =
            __builtin_amdgcn_mfma_f32_16x16x32_bf16(pf[jq], vf[nd], oacc[jq][nd], 0, 0, 0);
  }

  // ---- cross-wave merge ----
  if (lg == 0) {
#pragma unroll
    for (int jq = 0; jq < 4; ++jq) {
      smx[wave][jq * 16 + ln] = m_[jq];
      slx[wave][jq * 16 + ln] = l_[jq];
    }
  }
  __syncthreads();

  float fac[4];
#pragma unroll
  for (int jq = 0; jq < 4; ++jq) {
    const int q = jq * 16 + ln;
    const float a0 = smx[0][q], a1 = smx[1][q], a2 = smx[2][q], a3 = smx[3][q];
    const float M = fmaxf(fmaxf(a0, a1), fmaxf(a2, a3));
    const float L = slx[0][q] * __builtin_amdgcn_exp2f(a0 - M) +
                    slx[1][q] * __builtin_amdgcn_exp2f(a1 - M) +
                    slx[2][q] * __builtin_amdgcn_exp2f(a2 - M) +
                    slx[3][q] * __builtin_amdgcn_exp2f(a3 - M);
    fac[jq] = __builtin_amdgcn_exp2f(m_[jq] - M);
    if (wave == 0 && lg == 0) sLf[q] = L;
  }
  float facr[4][4];
#pragma unroll
  for (int jq = 0; jq < 4; ++jq)
#pragma unroll
    for (int r = 0; r < 4; ++r) facr[jq][r] = __shfl(fac[jq], lg * 4 + r);

  // accumulate partials into Om (f32), 4 rounds
  for (int w2 = 0; w2 < 4; ++w2) {
    if (wave == w2) {
#pragma unroll
      for (int jq = 0; jq < 4; ++jq)
#pragma unroll
        for (int nd = 0; nd < 4; ++nd)
#pragma unroll
          for (int r = 0; r < 4; ++r) {
            float* p = &Om[(jq * 16 + lg * 4 + r) * LDO + nd * 16 + ln];
            const float v = oacc[jq][nd][r] * facr[jq][r];
            if (w2 == 0) *p = v; else *p += v;
          }
    }
    __syncthreads();
  }

  // final: normalize, bf16, store AO (coalesced 32B/thread)
  {
    const int q = tid >> 2;
    const int dch = (tid & 3) * 16;
    const float Linv = 1.f / sLf[q];
    u32x4 w0, w1;
#pragma unroll
    for (int kk4 = 0; kk4 < 4; ++kk4) {
      f32x4 v = *(const f32x4*)&Om[q * LDO + dch + kk4 * 4];
      const unsigned p0 = cvtpk_bf16(v[0] * Linv, v[1] * Linv);
      const unsigned p1 = cvtpk_bf16(v[2] * Linv, v[3] * Linv);
      if (kk4 < 2) { w0[kk4 * 2] = p0; w0[kk4 * 2 + 1] = p1; }
      else { w1[(kk4 - 2) * 2] = p0; w1[(kk4 - 2) * 2 + 1] = p1; }
    }
    u16* dst = AO + (size_t)(q0 + q) * DIM + h * HD + dch;
    *(u32x4*)dst = w0;
    *(u32x4*)(dst + 8) = w1;
  }
}

extern "C" void kernel_launch(void* const* d_in, const int* in_sizes, int n_in,
                              void* d_out, int out_size, void* d_ws, size_t ws_size,
                              hipStream_t stream) {
  const float* x = (const float*)d_in[0];
  const float* wq = (const float*)d_in[1];
  const float* bq = (const float*)d_in[2];
  const float* wk = (const float*)d_in[3];
  const float* bk = (const float*)d_in[4];
  const float* wv = (const float*)d_in[5];
  const float* bv = (const float*)d_in[6];
  const float* ww = (const float*)d_in[7];
  const float* bw = (const float*)d_in[8];

  const size_t mat = (size_t)SEQ * DIM;
  if (ws_size < 4 * mat * sizeof(u16)) {
    fprintf(stderr, "kernel_launch: ws too small (%zu)\n", ws_size);
    return;
  }
  u16* Qb = (u16*)d_ws;
  u16* Kb = Qb + mat;
  u16* Vtb = Kb + mat;  // [768][4096]
  u16* AOb = Vtb + mat;

  dim3 gg(DIM / 128, SEQ / 128), bb(256);
  gemm_bias<false, 1><<<gg, bb, 0, stream>>>(x, wq, bq, Qb, SM_PRE);  // Q prescaled
  gemm_bias<false, 1><<<gg, bb, 0, stream>>>(x, wk, bk, Kb, 1.0f);
  gemm_bias<false, 2><<<gg, bb, 0, stream>>>(x, wv, bv, Vtb, 1.0f);
  attn_kernel<<<dim3(SEQ / 64, NH), bb, 0, stream>>>(Qb, Kb, Vtb, AOb);
  gemm_bias<true, 0><<<gg, bb, 0, stream>>>(AOb, ww, bw, (float*)d_out, 1.0f);
}

// Round 4
// 148.585 us; speedup vs baseline: 1.7216x; 1.7216x over previous
//
#include <hip/hip_runtime.h>
#include <cstdio>

// MHA block for MI355X (gfx950). Round 3:
//  - attn: 32x32x16 MFMA, 32 q/wave, swapped QK^T, P fully in-register via
//    cvt_pk + permlane32_swap (no P LDS), LDS-staged K/V with reg prefetch,
//    XCD-swizzled grid.
//  - gemm: bf16 pre-convert (x -> AO alias, w -> d_out scratch), fused QKV
//    GEMM (A staged once for 3 outputs), out-proj from bf16.
// ws (bf16): Q[S][768] | K[S][768] | Vt[768][S] | AO[S][768] (AO doubles as xb).

using u16 = unsigned short;
typedef __bf16 bf16x8 __attribute__((ext_vector_type(8)));
typedef float f32x4 __attribute__((ext_vector_type(4)));
typedef float f32x16 __attribute__((ext_vector_type(16)));
typedef unsigned int u32x4 __attribute__((ext_vector_type(4)));
typedef unsigned int u32x2 __attribute__((ext_vector_type(2)));
typedef u16 u16x4 __attribute__((ext_vector_type(4)));

constexpr int SEQ = 4096;
constexpr int DIM = 768;
constexpr int NH = 12;
constexpr int HD = 64;
constexpr int LDT = 72;  // LDS stride (bf16 elems): 144B rows, 16B-aligned
// (1/sqrt(64)) * log2(e), folded into Q projection
constexpr float SM_PRE = 0.18033688011112042f;
constexpr float DEFER_THR = 8.0f;

__device__ __forceinline__ u16 f2bf(float f) {
  union { float f; unsigned u; } v{f};
  unsigned r = v.u + 0x7fffu + ((v.u >> 16) & 1u);  // RNE
  return (u16)(r >> 16);
}
__device__ __forceinline__ unsigned cvtpk_bf16(float a, float b) {
  unsigned r;
  asm("v_cvt_pk_bf16_f32 %0, %1, %2" : "=v"(r) : "v"(a), "v"(b));
  return r;  // lo16 = bf16(a), hi16 = bf16(b)
}
// v_permlane32_swap: a' = {a.lo32lanes, b.lo32lanes-from-partner}, i.e.
// a'[i<32]=a[i], a'[i>=32]=b[i-32]; b'[i<32]=a[i+32], b'[i>=32]=b[i].
__device__ __forceinline__ void swap32(unsigned& a, unsigned& b) {
  asm volatile("v_permlane32_swap_b32 %0, %1" : "+v"(a), "+v"(b));
}

// ---------------- prep: fp32 -> bf16 converts ----------------
// blocks [0,1536): x -> xb ; [1536,1824): wq ; [1824,2112): wk ; [2112,2400): wv
__global__ __launch_bounds__(256) void prep_all(const float* __restrict__ x,
                                                const float* __restrict__ wq,
                                                const float* __restrict__ wk,
                                                const float* __restrict__ wv,
                                                u16* __restrict__ xb,
                                                u16* __restrict__ wqb,
                                                u16* __restrict__ wkb,
                                                u16* __restrict__ wvb) {
  constexpr size_t NX = (size_t)SEQ * DIM, NW = (size_t)DIM * DIM;
  size_t i = ((size_t)blockIdx.x * 256 + threadIdx.x) * 8;
  const float* src;
  u16* dst;
  size_t off;
  if (i < NX) { src = x; dst = xb; off = i; }
  else if (i < NX + NW) { src = wq; dst = wqb; off = i - NX; }
  else if (i < NX + 2 * NW) { src = wk; dst = wkb; off = i - NX - 2 * NW + NW; }
  else { src = wv; dst = wvb; off = i - NX - 3 * NW + NW; }
  float4 f0 = *(const float4*)(src + off);
  float4 f1 = *(const float4*)(src + off + 4);
  u32x4 w = {cvtpk_bf16(f0.x, f0.y), cvtpk_bf16(f0.z, f0.w),
             cvtpk_bf16(f1.x, f1.y), cvtpk_bf16(f1.z, f1.w)};
  *(u32x4*)(dst + off) = w;
}

__global__ __launch_bounds__(256) void prep_one(const float* __restrict__ w,
                                                u16* __restrict__ wb) {
  size_t off = ((size_t)blockIdx.x * 256 + threadIdx.x) * 8;
  float4 f0 = *(const float4*)(w + off);
  float4 f1 = *(const float4*)(w + off + 4);
  u32x4 v = {cvtpk_bf16(f0.x, f0.y), cvtpk_bf16(f0.z, f0.w),
             cvtpk_bf16(f1.x, f1.y), cvtpk_bf16(f1.z, f1.w)};
  *(u32x4*)(wb + off) = v;
}

// ---------------- fused QKV GEMM ----------------
// Q = SM_PRE*(xb @ wq^T + bq) bf16 row-major; K likewise (unscaled);
// V written transposed: Vt[col][row].
__global__ __launch_bounds__(256) void qkv_gemm(const u16* __restrict__ xb,
                                                const u16* __restrict__ wqb,
                                                const u16* __restrict__ wkb,
                                                const u16* __restrict__ wvb,
                                                const float* __restrict__ bq,
                                                const float* __restrict__ bk,
                                                const float* __restrict__ bv,
                                                u16* __restrict__ Qb,
                                                u16* __restrict__ Kb,
                                                u16* __restrict__ Vtb) {
  __shared__ alignas(16) u16 As[64 * LDT];
  __shared__ alignas(16) u16 Bq[64 * LDT];
  __shared__ alignas(16) u16 Bk[64 * LDT];
  __shared__ alignas(16) u16 Bv[64 * LDT];

  const int tid = threadIdx.x, lane = tid & 63, wave = tid >> 6;
  const int lg = lane >> 4, ln = lane & 15;
  // XCD swizzle: 768 blocks -> 8 chunks of 96
  const int bid = blockIdx.x;
  const int swz = (bid & 7) * 96 + (bid >> 3);
  const int mt = swz / 12, nt = swz % 12;
  const int m0 = mt * 64, n0 = nt * 64;
  const int sr = tid >> 2, sc = (tid & 3) * 16;

  f32x4 aq[4] = {}, ak[4] = {}, av[4] = {};

  for (int kk = 0; kk < DIM; kk += 64) {
    {
      const u32x4* s = (const u32x4*)(xb + (size_t)(m0 + sr) * DIM + kk + sc);
      *(u32x4*)&As[sr * LDT + sc] = s[0];
      *(u32x4*)&As[sr * LDT + sc + 8] = s[1];
    }
    {
      const u32x4* s = (const u32x4*)(wqb + (size_t)(n0 + sr) * DIM + kk + sc);
      *(u32x4*)&Bq[sr * LDT + sc] = s[0];
      *(u32x4*)&Bq[sr * LDT + sc + 8] = s[1];
    }
    {
      const u32x4* s = (const u32x4*)(wkb + (size_t)(n0 + sr) * DIM + kk + sc);
      *(u32x4*)&Bk[sr * LDT + sc] = s[0];
      *(u32x4*)&Bk[sr * LDT + sc + 8] = s[1];
    }
    {
      const u32x4* s = (const u32x4*)(wvb + (size_t)(n0 + sr) * DIM + kk + sc);
      *(u32x4*)&Bv[sr * LDT + sc] = s[0];
      *(u32x4*)&Bv[sr * LDT + sc + 8] = s[1];
    }
    __syncthreads();

#pragma unroll
    for (int c = 0; c < 2; ++c) {
      const int k0 = c * 32 + lg * 8;
      bf16x8 a = __builtin_bit_cast(bf16x8, *(const u32x4*)&As[(wave * 16 + ln) * LDT + k0]);
#pragma unroll
      for (int j = 0; j < 4; ++j) {
        bf16x8 q = __builtin_bit_cast(bf16x8, *(const u32x4*)&Bq[(j * 16 + ln) * LDT + k0]);
        aq[j] = __builtin_amdgcn_mfma_f32_16x16x32_bf16(a, q, aq[j], 0, 0, 0);
        bf16x8 k = __builtin_bit_cast(bf16x8, *(const u32x4*)&Bk[(j * 16 + ln) * LDT + k0]);
        ak[j] = __builtin_amdgcn_mfma_f32_16x16x32_bf16(a, k, ak[j], 0, 0, 0);
        bf16x8 v = __builtin_bit_cast(bf16x8, *(const u32x4*)&Bv[(j * 16 + ln) * LDT + k0]);
        av[j] = __builtin_amdgcn_mfma_f32_16x16x32_bf16(a, v, av[j], 0, 0, 0);
      }
    }
    __syncthreads();
  }

  const int rowb = m0 + wave * 16 + lg * 4;
#pragma unroll
  for (int j = 0; j < 4; ++j) {
    const int col = n0 + j * 16 + ln;
    const float bvq = bq[col], bvk = bk[col], bvv = bv[col];
#pragma unroll
    for (int r = 0; r < 4; ++r) {
      Qb[(size_t)(rowb + r) * DIM + col] = f2bf((aq[j][r] + bvq) * SM_PRE);
      Kb[(size_t)(rowb + r) * DIM + col] = f2bf(ak[j][r] + bvk);
    }
    u16x4 pk;
#pragma unroll
    for (int r = 0; r < 4; ++r) pk[r] = f2bf(av[j][r] + bvv);
    *(u16x4*)&Vtb[(size_t)col * SEQ + rowb] = pk;
  }
}

// ---------------- out projection ----------------
__global__ __launch_bounds__(256) void out_gemm(const u16* __restrict__ Ab,
                                                const u16* __restrict__ Wb,
                                                const float* __restrict__ bias,
                                                float* __restrict__ out) {
  __shared__ alignas(16) u16 As[64 * LDT];
  __shared__ alignas(16) u16 Bs[64 * LDT];

  const int tid = threadIdx.x, lane = tid & 63, wave = tid >> 6;
  const int lg = lane >> 4, ln = lane & 15;
  const int bid = blockIdx.x;
  const int swz = (bid & 7) * 96 + (bid >> 3);
  const int mt = swz / 12, nt = swz % 12;
  const int m0 = mt * 64, n0 = nt * 64;
  const int sr = tid >> 2, sc = (tid & 3) * 16;

  f32x4 acc[4] = {};

  for (int kk = 0; kk < DIM; kk += 64) {
    {
      const u32x4* s = (const u32x4*)(Ab + (size_t)(m0 + sr) * DIM + kk + sc);
      *(u32x4*)&As[sr * LDT + sc] = s[0];
      *(u32x4*)&As[sr * LDT + sc + 8] = s[1];
    }
    {
      const u32x4* s = (const u32x4*)(Wb + (size_t)(n0 + sr) * DIM + kk + sc);
      *(u32x4*)&Bs[sr * LDT + sc] = s[0];
      *(u32x4*)&Bs[sr * LDT + sc + 8] = s[1];
    }
    __syncthreads();
#pragma unroll
    for (int c = 0; c < 2; ++c) {
      const int k0 = c * 32 + lg * 8;
      bf16x8 a = __builtin_bit_cast(bf16x8, *(const u32x4*)&As[(wave * 16 + ln) * LDT + k0]);
#pragma unroll
      for (int j = 0; j < 4; ++j) {
        bf16x8 b = __builtin_bit_cast(bf16x8, *(const u32x4*)&Bs[(j * 16 + ln) * LDT + k0]);
        acc[j] = __builtin_amdgcn_mfma_f32_16x16x32_bf16(a, b, acc[j], 0, 0, 0);
      }
    }
    __syncthreads();
  }

  const int rowb = m0 + wave * 16 + lg * 4;
#pragma unroll
  for (int j = 0; j < 4; ++j) {
    const int col = n0 + j * 16 + ln;
    const float bv = bias[col];
#pragma unroll
    for (int r = 0; r < 4; ++r) out[(size_t)(rowb + r) * DIM + col] = acc[j][r] + bv;
  }
}

// ---------------- flash attention: 32x32 MFMA, in-register P ----------------
// Grid 384 blocks (32 q-tiles x 12 heads, XCD-swizzled), 4 waves x 32 q-rows.
// Q prescaled by SM_PRE (exp2 domain). Q,K: [S][768] bf16; Vt: [768][S] bf16.
__global__ __launch_bounds__(256, 3) void attn_kernel(const u16* __restrict__ Q,
                                                      const u16* __restrict__ K,
                                                      const u16* __restrict__ Vt,
                                                      u16* __restrict__ AO) {
  __shared__ alignas(16) u16 Ks[64 * LDT];  // [key][d]
  __shared__ alignas(16) u16 Vs[64 * LDT];  // [d][key]

  const int tid = threadIdx.x, lane = tid & 63, wave = tid >> 6;
  const int l31 = lane & 31, hi = lane >> 5;
  const int bid = blockIdx.x;
  const int swz = (bid & 7) * 48 + (bid >> 3);  // 384 = 8 * 48
  const int h = swz >> 5;        // /32
  const int qt = swz & 31;
  const int q0 = qt * 128;
  const int qw = q0 + wave * 32;

  // Q B-frags: qf[c] -> q col = l31, k(d) = c*16 + hi*8 + e
  bf16x8 qf[4];
#pragma unroll
  for (int c = 0; c < 4; ++c)
    qf[c] = __builtin_bit_cast(
        bf16x8, *(const u32x4*)(Q + (size_t)(qw + l31) * DIM + h * HD + c * 16 + hi * 8));

  float m_ = -1e30f, l_ = 0.f;
  f32x16 oacc[2] = {};  // [nd]: O[q=(r&3)+8*(r>>2)+4*hi][d=nd*32+l31]

  const int sr = tid >> 2, sc = (tid & 3) * 16;
  constexpr int NT = SEQ / 64;
  const u16* Kh = K + h * HD;
  const u16* Vh = Vt + (size_t)h * HD * SEQ;

  u32x4 ka, kb, va, vb;
  {
    const u32x4* s = (const u32x4*)(Kh + (size_t)sr * DIM + sc);
    ka = s[0]; kb = s[1];
    const u32x4* t = (const u32x4*)(Vh + (size_t)sr * SEQ + sc);
    va = t[0]; vb = t[1];
  }

  for (int kt = 0; kt < NT; ++kt) {
    __syncthreads();
    *(u32x4*)&Ks[sr * LDT + sc] = ka;
    *(u32x4*)&Ks[sr * LDT + sc + 8] = kb;
    *(u32x4*)&Vs[sr * LDT + sc] = va;
    *(u32x4*)&Vs[sr * LDT + sc + 8] = vb;
    __syncthreads();

    {  // prefetch next tile (T14)
      const int ktn = (kt + 1 < NT) ? kt + 1 : kt;
      const u32x4* s = (const u32x4*)(Kh + (size_t)(ktn * 64 + sr) * DIM + sc);
      ka = s[0]; kb = s[1];
      const u32x4* t = (const u32x4*)(Vh + (size_t)sr * SEQ + ktn * 64 + sc);
      va = t[0]; vb = t[1];
    }

    // S^T = K Q^T per 32-key subtile: col=l31 -> q, row(reg,hi) -> key
    f32x16 st0 = {}, st1 = {};
#pragma unroll
    for (int c = 0; c < 4; ++c) {
      bf16x8 kf0 = __builtin_bit_cast(
          bf16x8, *(const u32x4*)&Ks[(0 + l31) * LDT + c * 16 + hi * 8]);
      st0 = __builtin_amdgcn_mfma_f32_32x32x16_bf16(kf0, qf[c], st0, 0, 0, 0);
      bf16x8 kf1 = __builtin_bit_cast(
          bf16x8, *(const u32x4*)&Ks[(32 + l31) * LDT + c * 16 + hi * 8]);
      st1 = __builtin_amdgcn_mfma_f32_32x32x16_bf16(kf1, qf[c], st1, 0, 0, 0);
    }

    // tile max over the lane's 32 keys (tree), then combine hi-halves
    float t8[8];
#pragma unroll
    for (int r = 0; r < 8; ++r)
      t8[r] = fmaxf(fmaxf(st0[r], st0[r + 8]), fmaxf(st1[r], st1[r + 8]));
    float t4a = fmaxf(t8[0], t8[4]), t4b = fmaxf(t8[1], t8[5]);
    float t4c = fmaxf(t8[2], t8[6]), t4d = fmaxf(t8[3], t8[7]);
    float pmax = fmaxf(fmaxf(t4a, t4b), fmaxf(t4c, t4d));
    pmax = fmaxf(pmax, __shfl_xor(pmax, 32));

    if (__ballot(pmax > m_ + DEFER_THR)) {  // rare after first tiles (T13)
      const float mn = fmaxf(m_, pmax);
      const float scl = __builtin_amdgcn_exp2f(m_ - mn);
      l_ *= scl;
      m_ = mn;
      float fac[16];
#pragma unroll
      for (int r = 0; r < 16; ++r)
        fac[r] = __shfl(scl, (r & 3) + 8 * (r >> 2) + 4 * hi);
#pragma unroll
      for (int nd = 0; nd < 2; ++nd)
#pragma unroll
        for (int r = 0; r < 16; ++r) oacc[nd][r] *= fac[r];
    }

    // P = exp2(s - m) in place; row-sum tree
#pragma unroll
    for (int r = 0; r < 16; ++r) {
      st0[r] = __builtin_amdgcn_exp2f(st0[r] - m_);
      st1[r] = __builtin_amdgcn_exp2f(st1[r] - m_);
    }
    {
      float s8[8];
#pragma unroll
      for (int r = 0; r < 8; ++r)
        s8[r] = (st0[r] + st0[r + 8]) + (st1[r] + st1[r + 8]);
      float rs = ((s8[0] + s8[4]) + (s8[1] + s8[5])) + ((s8[2] + s8[6]) + (s8[3] + s8[7]));
      rs += __shfl_xor(rs, 32);
      l_ += rs;
    }

    // build PV A-frags in-register: cvt_pk pairs + permlane32_swap (T12)
    unsigned c0 = cvtpk_bf16(st0[0], st0[1]), c1 = cvtpk_bf16(st0[2], st0[3]);
    unsigned c2 = cvtpk_bf16(st0[4], st0[5]), c3 = cvtpk_bf16(st0[6], st0[7]);
    unsigned c4 = cvtpk_bf16(st0[8], st0[9]), c5 = cvtpk_bf16(st0[10], st0[11]);
    unsigned c6 = cvtpk_bf16(st0[12], st0[13]), c7 = cvtpk_bf16(st0[14], st0[15]);
    swap32(c0, c2); swap32(c1, c3); swap32(c4, c6); swap32(c5, c7);
    unsigned d0 = cvtpk_bf16(st1[0], st1[1]), d1 = cvtpk_bf16(st1[2], st1[3]);
    unsigned d2 = cvtpk_bf16(st1[4], st1[5]), d3 = cvtpk_bf16(st1[6], st1[7]);
    unsigned d4 = cvtpk_bf16(st1[8], st1[9]), d5 = cvtpk_bf16(st1[10], st1[11]);
    unsigned d6 = cvtpk_bf16(st1[12], st1[13]), d7 = cvtpk_bf16(st1[14], st1[15]);
    swap32(d0, d2); swap32(d1, d3); swap32(d4, d6); swap32(d5, d7);
    bf16x8 pa00 = __builtin_bit_cast(bf16x8, u32x4{c0, c1, c2, c3});  // keys 0-15
    bf16x8 pa01 = __builtin_bit_cast(bf16x8, u32x4{c4, c5, c6, c7});  // keys 16-31
    bf16x8 pa10 = __builtin_bit_cast(bf16x8, u32x4{d0, d1, d2, d3});  // keys 32-47
    bf16x8 pa11 = __builtin_bit_cast(bf16x8, u32x4{d4, d5, d6, d7});  // keys 48-63

    // O += P V : B-frag from Vs row d=nd*32+l31, keys chunk + hi*8
#pragma unroll
    for (int nd = 0; nd < 2; ++nd) {
      const int vrow = (nd * 32 + l31) * LDT;
      bf16x8 v0 = __builtin_bit_cast(bf16x8, *(const u32x4*)&Vs[vrow + 0 + hi * 8]);
      oacc[nd] = __builtin_amdgcn_mfma_f32_32x32x16_bf16(pa00, v0, oacc[nd], 0, 0, 0);
      bf16x8 v1 = __builtin_bit_cast(bf16x8, *(const u32x4*)&Vs[vrow + 16 + hi * 8]);
      oacc[nd] = __builtin_amdgcn_mfma_f32_32x32x16_bf16(pa01, v1, oacc[nd], 0, 0, 0);
      bf16x8 v2 = __builtin_bit_cast(bf16x8, *(const u32x4*)&Vs[vrow + 32 + hi * 8]);
      oacc[nd] = __builtin_amdgcn_mfma_f32_32x32x16_bf16(pa10, v2, oacc[nd], 0, 0, 0);
      bf16x8 v3 = __builtin_bit_cast(bf16x8, *(const u32x4*)&Vs[vrow + 48 + hi * 8]);
      oacc[nd] = __builtin_amdgcn_mfma_f32_32x32x16_bf16(pa11, v3, oacc[nd], 0, 0, 0);
    }
  }

  // epilogue: normalize rows, store bf16
  const float inv = 1.f / l_;  // stats for q = l31 (duplicated across hi)
  float invr[16];
#pragma unroll
  for (int r = 0; r < 16; ++r)
    invr[r] = __shfl(inv, (r & 3) + 8 * (r >> 2) + 4 * hi);
#pragma unroll
  for (int nd = 0; nd < 2; ++nd)
#pragma unroll
    for (int r = 0; r < 16; ++r) {
      const int row = qw + (r & 3) + 8 * (r >> 2) + 4 * hi;
      AO[(size_t)row * DIM + h * HD + nd * 32 + l31] = f2bf(oacc[nd][r] * invr[r]);
    }
}

extern "C" void kernel_launch(void* const* d_in, const int* in_sizes, int n_in,
                              void* d_out, int out_size, void* d_ws, size_t ws_size,
                              hipStream_t stream) {
  const float* x = (const float*)d_in[0];
  const float* wq = (const float*)d_in[1];
  const float* bq = (const float*)d_in[2];
  const float* wk = (const float*)d_in[3];
  const float* bk = (const float*)d_in[4];
  const float* wv = (const float*)d_in[5];
  const float* bv = (const float*)d_in[6];
  const float* ww = (const float*)d_in[7];
  const float* bw = (const float*)d_in[8];

  const size_t mat = (size_t)SEQ * DIM;   // 3,145,728 elems
  const size_t nw = (size_t)DIM * DIM;    // 589,824 elems
  if (ws_size < 4 * mat * sizeof(u16)) {
    fprintf(stderr, "kernel_launch: ws too small (%zu)\n", ws_size);
    return;
  }
  u16* Qb = (u16*)d_ws;
  u16* Kb = Qb + mat;
  u16* Vtb = Kb + mat;       // [768][4096]
  u16* AOb = Vtb + mat;      // also xb (same size, sequentially dead)
  u16* xb = AOb;             // alias: xb consumed by qkv_gemm before attn writes AO
  u16* wqb = (u16*)d_out;    // d_out as scratch during QKV+attn phases
  u16* wkb = wqb + nw;
  u16* wvb = wkb + nw;
  u16* wwb = Kb;             // K dead after attn; filled by prep_one

  prep_all<<<dim3(2400), dim3(256), 0, stream>>>(x, wq, wk, wv, xb, wqb, wkb, wvb);
  qkv_gemm<<<dim3(768), dim3(256), 0, stream>>>(xb, wqb, wkb, wvb, bq, bk, bv, Qb, Kb, Vtb);
  attn_kernel<<<dim3(384), dim3(256), 0, stream>>>(Qb, Kb, Vtb, AOb);
  prep_one<<<dim3(288), dim3(256), 0, stream>>>(ww, wwb);
  out_gemm<<<dim3(768), dim3(256), 0, stream>>>(AOb, wwb, bw, (float*)d_out);
}

// Round 5
// 141.511 us; speedup vs baseline: 1.8076x; 1.0500x over previous
//
#include <hip/hip_runtime.h>
#include <cstdio>

// MHA block for MI355X (gfx950). Round 4:
//  - attn: QBLK=64, grid 768 (3 blocks/CU balanced), 4 waves = 2 q-groups x
//    2 KV-parities (128 keys/barrier-round), double-parity LDS K/V, in-register
//    P (cvt_pk + permlane32_swap), T13 defer-max, T5 setprio, end merge via
//    LDS overlay.
//  - gemm: unchanged from R3 (bf16 pre-convert + fused QKV + out-proj).
// ws (bf16): Q[S][768] | K[S][768] | Vt[768][S] | AO[S][768] (AO doubles as xb).

using u16 = unsigned short;
typedef __bf16 bf16x8 __attribute__((ext_vector_type(8)));
typedef float f32x4 __attribute__((ext_vector_type(4)));
typedef float f32x16 __attribute__((ext_vector_type(16)));
typedef unsigned int u32x4 __attribute__((ext_vector_type(4)));
typedef u16 u16x4 __attribute__((ext_vector_type(4)));

constexpr int SEQ = 4096;
constexpr int DIM = 768;
constexpr int NH = 12;
constexpr int HD = 64;
constexpr int LDT = 72;  // LDS stride (bf16 elems): 144B rows, 16B-aligned
constexpr int LDO = 68;  // merge stride (f32): 2-way banks only
// (1/sqrt(64)) * log2(e), folded into Q projection
constexpr float SM_PRE = 0.18033688011112042f;
constexpr float DEFER_THR = 8.0f;

__device__ __forceinline__ u16 f2bf(float f) {
  union { float f; unsigned u; } v{f};
  unsigned r = v.u + 0x7fffu + ((v.u >> 16) & 1u);  // RNE
  return (u16)(r >> 16);
}
__device__ __forceinline__ unsigned cvtpk_bf16(float a, float b) {
  unsigned r;
  asm("v_cvt_pk_bf16_f32 %0, %1, %2" : "=v"(r) : "v"(a), "v"(b));
  return r;
}
__device__ __forceinline__ void swap32(unsigned& a, unsigned& b) {
  asm volatile("v_permlane32_swap_b32 %0, %1" : "+v"(a), "+v"(b));
}

// ---------------- prep: fp32 -> bf16 converts ----------------
__global__ __launch_bounds__(256) void prep_all(const float* __restrict__ x,
                                                const float* __restrict__ wq,
                                                const float* __restrict__ wk,
                                                const float* __restrict__ wv,
                                                u16* __restrict__ xb,
                                                u16* __restrict__ wqb,
                                                u16* __restrict__ wkb,
                                                u16* __restrict__ wvb) {
  constexpr size_t NX = (size_t)SEQ * DIM, NW = (size_t)DIM * DIM;
  size_t i = ((size_t)blockIdx.x * 256 + threadIdx.x) * 8;
  const float* src;
  u16* dst;
  size_t off;
  if (i < NX) { src = x; dst = xb; off = i; }
  else if (i < NX + NW) { src = wq; dst = wqb; off = i - NX; }
  else if (i < NX + 2 * NW) { src = wk; dst = wkb; off = i - NX - 2 * NW + NW; }
  else { src = wv; dst = wvb; off = i - NX - 3 * NW + NW; }
  float4 f0 = *(const float4*)(src + off);
  float4 f1 = *(const float4*)(src + off + 4);
  u32x4 w = {cvtpk_bf16(f0.x, f0.y), cvtpk_bf16(f0.z, f0.w),
             cvtpk_bf16(f1.x, f1.y), cvtpk_bf16(f1.z, f1.w)};
  *(u32x4*)(dst + off) = w;
}

__global__ __launch_bounds__(256) void prep_one(const float* __restrict__ w,
                                                u16* __restrict__ wb) {
  size_t off = ((size_t)blockIdx.x * 256 + threadIdx.x) * 8;
  float4 f0 = *(const float4*)(w + off);
  float4 f1 = *(const float4*)(w + off + 4);
  u32x4 v = {cvtpk_bf16(f0.x, f0.y), cvtpk_bf16(f0.z, f0.w),
             cvtpk_bf16(f1.x, f1.y), cvtpk_bf16(f1.z, f1.w)};
  *(u32x4*)(wb + off) = v;
}

// ---------------- fused QKV GEMM (unchanged from R3) ----------------
__global__ __launch_bounds__(256) void qkv_gemm(const u16* __restrict__ xb,
                                                const u16* __restrict__ wqb,
                                                const u16* __restrict__ wkb,
                                                const u16* __restrict__ wvb,
                                                const float* __restrict__ bq,
                                                const float* __restrict__ bk,
                                                const float* __restrict__ bv,
                                                u16* __restrict__ Qb,
                                                u16* __restrict__ Kb,
                                                u16* __restrict__ Vtb) {
  __shared__ alignas(16) u16 As[64 * LDT];
  __shared__ alignas(16) u16 Bq[64 * LDT];
  __shared__ alignas(16) u16 Bk[64 * LDT];
  __shared__ alignas(16) u16 Bv[64 * LDT];

  const int tid = threadIdx.x, lane = tid & 63, wave = tid >> 6;
  const int lg = lane >> 4, ln = lane & 15;
  const int bid = blockIdx.x;
  const int swz = (bid & 7) * 96 + (bid >> 3);
  const int mt = swz / 12, nt = swz % 12;
  const int m0 = mt * 64, n0 = nt * 64;
  const int sr = tid >> 2, sc = (tid & 3) * 16;

  f32x4 aq[4] = {}, ak[4] = {}, av[4] = {};

  for (int kk = 0; kk < DIM; kk += 64) {
    {
      const u32x4* s = (const u32x4*)(xb + (size_t)(m0 + sr) * DIM + kk + sc);
      *(u32x4*)&As[sr * LDT + sc] = s[0];
      *(u32x4*)&As[sr * LDT + sc + 8] = s[1];
    }
    {
      const u32x4* s = (const u32x4*)(wqb + (size_t)(n0 + sr) * DIM + kk + sc);
      *(u32x4*)&Bq[sr * LDT + sc] = s[0];
      *(u32x4*)&Bq[sr * LDT + sc + 8] = s[1];
    }
    {
      const u32x4* s = (const u32x4*)(wkb + (size_t)(n0 + sr) * DIM + kk + sc);
      *(u32x4*)&Bk[sr * LDT + sc] = s[0];
      *(u32x4*)&Bk[sr * LDT + sc + 8] = s[1];
    }
    {
      const u32x4* s = (const u32x4*)(wvb + (size_t)(n0 + sr) * DIM + kk + sc);
      *(u32x4*)&Bv[sr * LDT + sc] = s[0];
      *(u32x4*)&Bv[sr * LDT + sc + 8] = s[1];
    }
    __syncthreads();

#pragma unroll
    for (int c = 0; c < 2; ++c) {
      const int k0 = c * 32 + lg * 8;
      bf16x8 a = __builtin_bit_cast(bf16x8, *(const u32x4*)&As[(wave * 16 + ln) * LDT + k0]);
#pragma unroll
      for (int j = 0; j < 4; ++j) {
        bf16x8 q = __builtin_bit_cast(bf16x8, *(const u32x4*)&Bq[(j * 16 + ln) * LDT + k0]);
        aq[j] = __builtin_amdgcn_mfma_f32_16x16x32_bf16(a, q, aq[j], 0, 0, 0);
        bf16x8 k = __builtin_bit_cast(bf16x8, *(const u32x4*)&Bk[(j * 16 + ln) * LDT + k0]);
        ak[j] = __builtin_amdgcn_mfma_f32_16x16x32_bf16(a, k, ak[j], 0, 0, 0);
        bf16x8 v = __builtin_bit_cast(bf16x8, *(const u32x4*)&Bv[(j * 16 + ln) * LDT + k0]);
        av[j] = __builtin_amdgcn_mfma_f32_16x16x32_bf16(a, v, av[j], 0, 0, 0);
      }
    }
    __syncthreads();
  }

  const int rowb = m0 + wave * 16 + lg * 4;
#pragma unroll
  for (int j = 0; j < 4; ++j) {
    const int col = n0 + j * 16 + ln;
    const float bvq = bq[col], bvk = bk[col], bvv = bv[col];
#pragma unroll
    for (int r = 0; r < 4; ++r) {
      Qb[(size_t)(rowb + r) * DIM + col] = f2bf((aq[j][r] + bvq) * SM_PRE);
      Kb[(size_t)(rowb + r) * DIM + col] = f2bf(ak[j][r] + bvk);
    }
    u16x4 pk;
#pragma unroll
    for (int r = 0; r < 4; ++r) pk[r] = f2bf(av[j][r] + bvv);
    *(u16x4*)&Vtb[(size_t)col * SEQ + rowb] = pk;
  }
}

// ---------------- out projection (unchanged from R3) ----------------
__global__ __launch_bounds__(256) void out_gemm(const u16* __restrict__ Ab,
                                                const u16* __restrict__ Wb,
                                                const float* __restrict__ bias,
                                                float* __restrict__ out) {
  __shared__ alignas(16) u16 As[64 * LDT];
  __shared__ alignas(16) u16 Bs[64 * LDT];

  const int tid = threadIdx.x, lane = tid & 63, wave = tid >> 6;
  const int lg = lane >> 4, ln = lane & 15;
  const int bid = blockIdx.x;
  const int swz = (bid & 7) * 96 + (bid >> 3);
  const int mt = swz / 12, nt = swz % 12;
  const int m0 = mt * 64, n0 = nt * 64;
  const int sr = tid >> 2, sc = (tid & 3) * 16;

  f32x4 acc[4] = {};

  for (int kk = 0; kk < DIM; kk += 64) {
    {
      const u32x4* s = (const u32x4*)(Ab + (size_t)(m0 + sr) * DIM + kk + sc);
      *(u32x4*)&As[sr * LDT + sc] = s[0];
      *(u32x4*)&As[sr * LDT + sc + 8] = s[1];
    }
    {
      const u32x4* s = (const u32x4*)(Wb + (size_t)(n0 + sr) * DIM + kk + sc);
      *(u32x4*)&Bs[sr * LDT + sc] = s[0];
      *(u32x4*)&Bs[sr * LDT + sc + 8] = s[1];
    }
    __syncthreads();
#pragma unroll
    for (int c = 0; c < 2; ++c) {
      const int k0 = c * 32 + lg * 8;
      bf16x8 a = __builtin_bit_cast(bf16x8, *(const u32x4*)&As[(wave * 16 + ln) * LDT + k0]);
#pragma unroll
      for (int j = 0; j < 4; ++j) {
        bf16x8 b = __builtin_bit_cast(bf16x8, *(const u32x4*)&Bs[(j * 16 + ln) * LDT + k0]);
        acc[j] = __builtin_amdgcn_mfma_f32_16x16x32_bf16(a, b, acc[j], 0, 0, 0);
      }
    }
    __syncthreads();
  }

  const int rowb = m0 + wave * 16 + lg * 4;
#pragma unroll
  for (int j = 0; j < 4; ++j) {
    const int col = n0 + j * 16 + ln;
    const float bv = bias[col];
#pragma unroll
    for (int r = 0; r < 4; ++r) out[(size_t)(rowb + r) * DIM + col] = acc[j][r] + bv;
  }
}

// ---------------- flash attention: QBLK=64, 2 q-groups x 2 KV-parities ----------------
// Grid 768 (64 q-tiles x 12 heads, XCD-swizzled), 4 waves x 32 q-rows.
// Wave (g,p): q rows qt*64+g*32.., keys t*128+p*64.. per round. End merge p0+p1.
__global__ __launch_bounds__(256, 3) void attn_kernel(const u16* __restrict__ Q,
                                                      const u16* __restrict__ K,
                                                      const u16* __restrict__ Vt,
                                                      u16* __restrict__ AO) {
  __shared__ alignas(16) u16 Ksv[4][64 * LDT];  // [0]=K p0,[1]=K p1,[2]=V p0,[3]=V p1
  __shared__ float sm[4][32], sl[4][32];

  const int tid = threadIdx.x, lane = tid & 63, wave = tid >> 6;
  const int l31 = lane & 31, hi = lane >> 5;
  const int g = wave >> 1, p = wave & 1;
  const int bid = blockIdx.x;
  const int swz = (bid & 7) * 96 + (bid >> 3);  // 768 = 8*96
  const int h = swz >> 6;
  const int qt = swz & 63;
  const int qw = qt * 64 + g * 32;

  // Q B-frags: q col = l31, k(d) = c*16 + hi*8 + e
  bf16x8 qf[4];
#pragma unroll
  for (int c = 0; c < 4; ++c)
    qf[c] = __builtin_bit_cast(
        bf16x8, *(const u32x4*)(Q + (size_t)(qw + l31) * DIM + h * HD + c * 16 + hi * 8));

  float m_ = -1e30f, l_ = 0.f;
  f32x16 oacc[2] = {};  // [nd]: O[q=(r&3)+8*(r>>2)+4*hi][d=nd*32+l31]

  // staging: thread -> 64B of K + 64B of V (two-parity round = 128 keys)
  const int srow = tid >> 1;           // 0..127 (K key row within round)
  const int shalf = (tid & 1) * 32;    // elem offset (64B half-row)
  const int kpar = srow >> 6, krow = srow & 63;

  const u16* Kh = K + h * HD;
  const u16* Vh = Vt + (size_t)h * HD * SEQ;
  constexpr int NT = SEQ / 128;  // 32 rounds

  u32x4 kpre[4], vpre[4];
  auto prefetch = [&](int t) {
    const u32x4* s = (const u32x4*)(Kh + (size_t)(t * 128 + srow) * DIM + shalf);
    kpre[0] = s[0]; kpre[1] = s[1]; kpre[2] = s[2]; kpre[3] = s[3];
    const u32x4* v = (const u32x4*)(Vh + (size_t)krow * SEQ + t * 128 + kpar * 64 + shalf);
    vpre[0] = v[0]; vpre[1] = v[1]; vpre[2] = v[2]; vpre[3] = v[3];
  };
  prefetch(0);

  for (int t = 0; t < NT; ++t) {
    __syncthreads();  // everyone done reading previous round
    {
      u16* kd = &Ksv[kpar][krow * LDT + shalf];
      *(u32x4*)kd = kpre[0]; *(u32x4*)(kd + 8) = kpre[1];
      *(u32x4*)(kd + 16) = kpre[2]; *(u32x4*)(kd + 24) = kpre[3];
      u16* vd = &Ksv[2 + kpar][krow * LDT + shalf];
      *(u32x4*)vd = vpre[0]; *(u32x4*)(vd + 8) = vpre[1];
      *(u32x4*)(vd + 16) = vpre[2]; *(u32x4*)(vd + 24) = vpre[3];
    }
    __syncthreads();
    prefetch(t + 1 < NT ? t + 1 : t);  // completes under compute

    // S^T = K Q^T on parity-p tile: col=l31 -> q, row(reg,hi) -> key
    f32x16 st0 = {}, st1 = {};
    __builtin_amdgcn_s_setprio(1);
#pragma unroll
    for (int c = 0; c < 4; ++c) {
      bf16x8 kf0 = __builtin_bit_cast(
          bf16x8, *(const u32x4*)&Ksv[p][(0 + l31) * LDT + c * 16 + hi * 8]);
      st0 = __builtin_amdgcn_mfma_f32_32x32x16_bf16(kf0, qf[c], st0, 0, 0, 0);
      bf16x8 kf1 = __builtin_bit_cast(
          bf16x8, *(const u32x4*)&Ksv[p][(32 + l31) * LDT + c * 16 + hi * 8]);
      st1 = __builtin_amdgcn_mfma_f32_32x32x16_bf16(kf1, qf[c], st1, 0, 0, 0);
    }
    __builtin_amdgcn_s_setprio(0);

    // tile max over the lane's 32 keys, then combine hi-halves
    float t8[8];
#pragma unroll
    for (int r = 0; r < 8; ++r)
      t8[r] = fmaxf(fmaxf(st0[r], st0[r + 8]), fmaxf(st1[r], st1[r + 8]));
    float t4a = fmaxf(t8[0], t8[4]), t4b = fmaxf(t8[1], t8[5]);
    float t4c = fmaxf(t8[2], t8[6]), t4d = fmaxf(t8[3], t8[7]);
    float pmax = fmaxf(fmaxf(t4a, t4b), fmaxf(t4c, t4d));
    pmax = fmaxf(pmax, __shfl_xor(pmax, 32));

    if (__ballot(pmax > m_ + DEFER_THR)) {  // T13: rare after first rounds
      const float mn = fmaxf(m_, pmax);
      const float scl = __builtin_amdgcn_exp2f(m_ - mn);
      l_ *= scl;
      m_ = mn;
      float fac[16];
#pragma unroll
      for (int r = 0; r < 16; ++r)
        fac[r] = __shfl(scl, (r & 3) + 8 * (r >> 2) + 4 * hi);
#pragma unroll
      for (int nd = 0; nd < 2; ++nd)
#pragma unroll
        for (int r = 0; r < 16; ++r) oacc[nd][r] *= fac[r];
    }

    // P = exp2(s - m); row-sum tree
#pragma unroll
    for (int r = 0; r < 16; ++r) {
      st0[r] = __builtin_amdgcn_exp2f(st0[r] - m_);
      st1[r] = __builtin_amdgcn_exp2f(st1[r] - m_);
    }
    {
      float s8[8];
#pragma unroll
      for (int r = 0; r < 8; ++r)
        s8[r] = (st0[r] + st0[r + 8]) + (st1[r] + st1[r + 8]);
      float rs = ((s8[0] + s8[4]) + (s8[1] + s8[5])) + ((s8[2] + s8[6]) + (s8[3] + s8[7]));
      rs += __shfl_xor(rs, 32);
      l_ += rs;
    }

    // PV A-frags in-register: cvt_pk + permlane32_swap (T12)
    unsigned c0 = cvtpk_bf16(st0[0], st0[1]), c1 = cvtpk_bf16(st0[2], st0[3]);
    unsigned c2 = cvtpk_bf16(st0[4], st0[5]), c3 = cvtpk_bf16(st0[6], st0[7]);
    unsigned c4 = cvtpk_bf16(st0[8], st0[9]), c5 = cvtpk_bf16(st0[10], st0[11]);
    unsigned c6 = cvtpk_bf16(st0[12], st0[13]), c7 = cvtpk_bf16(st0[14], st0[15]);
    swap32(c0, c2); swap32(c1, c3); swap32(c4, c6); swap32(c5, c7);
    unsigned d0 = cvtpk_bf16(st1[0], st1[1]), d1 = cvtpk_bf16(st1[2], st1[3]);
    unsigned d2 = cvtpk_bf16(st1[4], st1[5]), d3 = cvtpk_bf16(st1[6], st1[7]);
    unsigned d4 = cvtpk_bf16(st1[8], st1[9]), d5 = cvtpk_bf16(st1[10], st1[11]);
    unsigned d6 = cvtpk_bf16(st1[12], st1[13]), d7 = cvtpk_bf16(st1[14], st1[15]);
    swap32(d0, d2); swap32(d1, d3); swap32(d4, d6); swap32(d5, d7);
    bf16x8 pa00 = __builtin_bit_cast(bf16x8, u32x4{c0, c1, c2, c3});
    bf16x8 pa01 = __builtin_bit_cast(bf16x8, u32x4{c4, c5, c6, c7});
    bf16x8 pa10 = __builtin_bit_cast(bf16x8, u32x4{d0, d1, d2, d3});
    bf16x8 pa11 = __builtin_bit_cast(bf16x8, u32x4{d4, d5, d6, d7});

    // O += P V on parity-p V tile
    __builtin_amdgcn_s_setprio(1);
#pragma unroll
    for (int nd = 0; nd < 2; ++nd) {
      const int vrow = (nd * 32 + l31) * LDT;
      bf16x8 v0 = __builtin_bit_cast(bf16x8, *(const u32x4*)&Ksv[2 + p][vrow + 0 + hi * 8]);
      oacc[nd] = __builtin_amdgcn_mfma_f32_32x32x16_bf16(pa00, v0, oacc[nd], 0, 0, 0);
      bf16x8 v1 = __builtin_bit_cast(bf16x8, *(const u32x4*)&Ksv[2 + p][vrow + 16 + hi * 8]);
      oacc[nd] = __builtin_amdgcn_mfma_f32_32x32x16_bf16(pa01, v1, oacc[nd], 0, 0, 0);
      bf16x8 v2 = __builtin_bit_cast(bf16x8, *(const u32x4*)&Ksv[2 + p][vrow + 32 + hi * 8]);
      oacc[nd] = __builtin_amdgcn_mfma_f32_32x32x16_bf16(pa10, v2, oacc[nd], 0, 0, 0);
      bf16x8 v3 = __builtin_bit_cast(bf16x8, *(const u32x4*)&Ksv[2 + p][vrow + 48 + hi * 8]);
      oacc[nd] = __builtin_amdgcn_mfma_f32_32x32x16_bf16(pa11, v3, oacc[nd], 0, 0, 0);
    }
    __builtin_amdgcn_s_setprio(0);
  }

  // ---- merge parity partners (g,0) + (g,1) ----
  if (hi == 0) { sm[wave][l31] = m_; sl[wave][l31] = l_; }
  __syncthreads();  // also guards Ksv reuse as Om below

  const float m0s = sm[g * 2][l31], m1s = sm[g * 2 + 1][l31];
  const float l0s = sl[g * 2][l31], l1s = sl[g * 2 + 1][l31];
  const float M = fmaxf(m0s, m1s);
  const float L = l0s * __builtin_amdgcn_exp2f(m0s - M) +
                  l1s * __builtin_amdgcn_exp2f(m1s - M);
  const float fac = __builtin_amdgcn_exp2f(m_ - M);
  const float Linv = 1.f / L;
  float facr[16], Linvr[16];
#pragma unroll
  for (int r = 0; r < 16; ++r) {
    const int ri = (r & 3) + 8 * (r >> 2) + 4 * hi;
    facr[r] = __shfl(fac, ri);
    Linvr[r] = __shfl(Linv, ri);
  }

  float* Om = (float*)Ksv;  // overlay staging buffers (17 KB of 36 KB)
  if (p == 1) {
#pragma unroll
    for (int nd = 0; nd < 2; ++nd)
#pragma unroll
      for (int r = 0; r < 16; ++r) {
        const int row = (r & 3) + 8 * (r >> 2) + 4 * hi;
        Om[(g * 32 + row) * LDO + nd * 32 + l31] = oacc[nd][r] * facr[r];
      }
  }
  __syncthreads();
  if (p == 0) {
#pragma unroll
    for (int nd = 0; nd < 2; ++nd)
#pragma unroll
      for (int r = 0; r < 16; ++r) {
        const int row = (r & 3) + 8 * (r >> 2) + 4 * hi;
        const float v = (oacc[nd][r] * facr[r] +
                         Om[(g * 32 + row) * LDO + nd * 32 + l31]) * Linvr[r];
        AO[(size_t)(qw + row) * DIM + h * HD + nd * 32 + l31] = f2bf(v);
      }
  }
}

extern "C" void kernel_launch(void* const* d_in, const int* in_sizes, int n_in,
                              void* d_out, int out_size, void* d_ws, size_t ws_size,
                              hipStream_t stream) {
  const float* x = (const float*)d_in[0];
  const float* wq = (const float*)d_in[1];
  const float* bq = (const float*)d_in[2];
  const float* wk = (const float*)d_in[3];
  const float* bk = (const float*)d_in[4];
  const float* wv = (const float*)d_in[5];
  const float* bv = (const float*)d_in[6];
  const float* ww = (const float*)d_in[7];
  const float* bw = (const float*)d_in[8];

  const size_t mat = (size_t)SEQ * DIM;
  const size_t nw = (size_t)DIM * DIM;
  if (ws_size < 4 * mat * sizeof(u16)) {
    fprintf(stderr, "kernel_launch: ws too small (%zu)\n", ws_size);
    return;
  }
  u16* Qb = (u16*)d_ws;
  u16* Kb = Qb + mat;
  u16* Vtb = Kb + mat;       // [768][4096]
  u16* AOb = Vtb + mat;      // also xb (sequentially dead)
  u16* xb = AOb;
  u16* wqb = (u16*)d_out;    // d_out as scratch during QKV+attn phases
  u16* wkb = wqb + nw;
  u16* wvb = wkb + nw;
  u16* wwb = Kb;             // K dead after attn

  prep_all<<<dim3(2400), dim3(256), 0, stream>>>(x, wq, wk, wv, xb, wqb, wkb, wvb);
  qkv_gemm<<<dim3(768), dim3(256), 0, stream>>>(xb, wqb, wkb, wvb, bq, bk, bv, Qb, Kb, Vtb);
  attn_kernel<<<dim3(768), dim3(256), 0, stream>>>(Qb, Kb, Vtb, AOb);
  prep_one<<<dim3(288), dim3(256), 0, stream>>>(ww, wwb);
  out_gemm<<<dim3(768), dim3(256), 0, stream>>>(AOb, wwb, bw, (float*)d_out);
}